// Round 4
// baseline (968.098 us; speedup 1.0000x reference)
//
#include <hip/hip_runtime.h>

// x shape (B, C, H, W) fp32
#define B    64
#define C    2048
#define H    24
#define W    12
#define S    288          // H*W spatial positions
#define S4   72           // float4 per channel slice
#define W4   3            // float4 per row
#define NCH  32           // channel chunks per sample
#define CCH  64           // channels per chunk
#define RH   8            // round(0.33 * 24)
#define T    576          // threads/block = 9 waves (multiple of 64)
#define G    8            // channel subgroups = T / S4
#define KPT  8            // float4 loads per thread = CCH*S4 / T

typedef float f4 __attribute__((ext_vector_type(4)));

// Zero the 128 control words (cnt[64] ++ ready[64]) — ws is poisoned 0xAA
// before every timed call, so this must run first each call.
__global__ __launch_bounds__(128) void k_init(unsigned int* flags) {
    flags[threadIdx.x] = 0u;
}

// ---------------------------------------------------------------------------
// Single fused kernel. Block (chunk, sample), 576 threads.
//   t -> f = t%72 (fixed float4 column => fixed row h = f/3), g = t/72.
//   Loads x4[t + 576k], k<8: contiguous 9.2 KB spans, perfectly coalesced;
//   data stays in REGISTERS (32 VGPRs) across the selection rendezvous, so
//   x is read from HBM exactly once and never re-fetched.
// Rendezvous: per-sample arrival counter; 32nd block computes the selection
//   from the 32 chunk partials and publishes 0x80000000|mask24 (single word =>
//   flag and payload can't be torn apart). Others poll with s_sleep backoff.
// Progress: sample's 32 blocks are consecutive dispatch indices; resident
//   window is ~2-3 blocks/CU * 256 CUs >> 32, and arrival happens at block
//   START, so the oldest incomplete sample always completes => no deadlock.
// ---------------------------------------------------------------------------
__global__ __launch_bounds__(T) void k_fused(const float* __restrict__ x,
                                             float* __restrict__ out,
                                             float* __restrict__ part,
                                             unsigned int* __restrict__ cnt,
                                             unsigned int* __restrict__ ready) {
    const int chunk = blockIdx.x;   // 0..NCH-1
    const int s     = blockIdx.y;   // 0..B-1
    const int t     = threadIdx.x;  // 0..575
    const int f     = t % S4;
    const int g     = t / S4;

    const size_t base4 = (size_t)(s * C + chunk * CCH) * S4;
    const f4* __restrict__ x4 = (const f4*)x + base4;
    f4* __restrict__       o4 = (f4*)out + base4;

    // ---- phase 1: load chunk into registers + energy accumulate ----
    f4 v[KPT];
    f4 acc = {0.f, 0.f, 0.f, 0.f};
    #pragma unroll
    for (int k = 0; k < KPT; ++k) {
        v[k] = x4[t + T * k];
        acc += v[k] * v[k];
    }

    __shared__ f4 sm[G][S4];            // 9.2 KB subgroup partials
    __shared__ unsigned int lmask;      // broadcast of ready word
    __shared__ int lastflag;
    sm[g][f] = acc;
    __syncthreads();

    if (t < S) {
        const float* smf = (const float*)sm;
        float sum = 0.f;
        #pragma unroll
        for (int gg = 0; gg < G; ++gg) sum += smf[gg * S + t];
        part[((size_t)s * NCH + chunk) * S + t] = sum;
    }
    __threadfence();                    // part visible device-wide before arrival
    __syncthreads();
    if (t == 0) {
        unsigned int old = __hip_atomic_fetch_add(
            &cnt[s], 1u, __ATOMIC_ACQ_REL, __HIP_MEMORY_SCOPE_AGENT);
        lastflag = (old == NCH - 1);
    }
    __syncthreads();

    // ---- last-arriving block of this sample: compute selection ----
    if (lastflag) {
        __shared__ float act[S];
        __shared__ float rm[H];
        __shared__ unsigned int dropbits;
        if (t == 0) dropbits = 0u;
        __syncthreads();
        if (t < S) {
            const float* p = part + (size_t)s * NCH * S + t;
            float sum = 0.f;
            #pragma unroll
            for (int ch = 0; ch < NCH; ++ch) sum += p[ch * S];  // ascending, as validated
            act[t] = sum;
        }
        __syncthreads();
        if (t < H) {
            float m = act[t * W];
            #pragma unroll
            for (int w = 1; w < W; ++w) m = fmaxf(m, act[t * W + w]);
            rm[t] = m;
        }
        __syncthreads();
        if (t < H) {
            // stable argsort(ascending)[-RH:] tie rule: equal value, larger idx wins
            const float mt = rm[t];
            int bigger = 0;
            #pragma unroll
            for (int j = 0; j < H; ++j) {
                float mj = rm[j];
                if (mj > mt || (mj == mt && j > t)) bigger++;
            }
            if (bigger < RH) atomicOr(&dropbits, 1u << t);
        }
        __syncthreads();
        if (t == 0) {
            __hip_atomic_store(&ready[s], 0x80000000u | dropbits,
                               __ATOMIC_RELEASE, __HIP_MEMORY_SCOPE_AGENT);
        }
    }

    // ---- wait for the sample's mask (thread-0 poll, LDS broadcast) ----
    if (t == 0) {
        unsigned int word;
        while ((word = __hip_atomic_load(&ready[s], __ATOMIC_ACQUIRE,
                                         __HIP_MEMORY_SCOPE_AGENT)) == 0u)
            __builtin_amdgcn_s_sleep(32);
        lmask = word;
    }
    __syncthreads();
    const unsigned int mask = lmask;

    // ---- phase 2: masked write from registers, nontemporal ----
    const int h = f / W4;                       // fixed per thread
    const float keep = ((mask >> h) & 1u) ? 0.f : 1.f;
    #pragma unroll
    for (int k = 0; k < KPT; ++k) {
        f4 r = v[k] * keep;                     // 0*finite == 0 exactly
        __builtin_nontemporal_store(r, &o4[t + T * k]);
    }
}

extern "C" void kernel_launch(void* const* d_in, const int* in_sizes, int n_in,
                              void* d_out, int out_size, void* d_ws, size_t ws_size,
                              hipStream_t stream) {
    const float* x   = (const float*)d_in[0];
    float*       out = (float*)d_out;

    // ws layout: [ part: B*NCH*S floats = 2.36 MB ][ cnt: 64 u32 ][ ready: 64 u32 ]
    float*        part  = (float*)d_ws;
    unsigned int* flags = (unsigned int*)((char*)d_ws + (size_t)B * NCH * S * sizeof(float));
    unsigned int* cnt   = flags;
    unsigned int* ready = flags + B;

    k_init<<<1, 128, 0, stream>>>(flags);
    k_fused<<<dim3(NCH, B), T, 0, stream>>>(x, out, part, cnt, ready);
}